// Round 3
// baseline (780.772 us; speedup 1.0000x reference)
//
#include <hip/hip_runtime.h>
#include <stdint.h>

typedef unsigned short u16;
typedef __attribute__((ext_vector_type(8))) short short8;
typedef __attribute__((ext_vector_type(4))) float f32x4;

static __device__ __forceinline__ u16 f2bf(float f){
  unsigned int x = __float_as_uint(f);
  unsigned int r = (x + 0x7FFFu + ((x >> 16) & 1u)) >> 16;
  return (u16)r;
}
static __device__ __forceinline__ float bf2f(u16 u){
  return __uint_as_float(((unsigned int)u) << 16);
}

// ---------------- convert f32 -> bf16 (vectorized) ----------------
__global__ __launch_bounds__(256) void cvt_f32_bf16(const float* __restrict__ in,
                                                    u16* __restrict__ out, int n){
  int i = (blockIdx.x * 256 + threadIdx.x) * 4;
  int stride = gridDim.x * 256 * 4;
  for (; i < n; i += stride){
    float4 v = *reinterpret_cast<const float4*>(in + i);
    union { u16 u[4]; unsigned long long ll; } o;
    o.u[0] = f2bf(v.x); o.u[1] = f2bf(v.y); o.u[2] = f2bf(v.z); o.u[3] = f2bf(v.w);
    *reinterpret_cast<unsigned long long*>(out + i) = o.ll;
  }
}

// ---------------- build combined [W_delta ; xproj_BC ; pad] (896 x 768) bf16 per layer ----
__global__ __launch_bounds__(256) void build_dbc(const float* __restrict__ dt_w,
                                                 const float* __restrict__ xproj_w,
                                                 u16* __restrict__ out){
  const int total = 4 * 896 * 768;
  for (int idx = blockIdx.x * 256 + threadIdx.x; idx < total; idx += gridDim.x * 256){
    int l = idx / (896 * 768);
    int rem = idx - l * 896 * 768;
    int row = rem / 768;
    int k = rem - row * 768;
    float v = 0.f;
    if (row < 768){
      const float* dtr = dt_w + ((size_t)l * 768 + row) * 48;
      const float* xp  = xproj_w + (size_t)l * 80 * 768 + k;
      #pragma unroll 8
      for (int j = 0; j < 48; j++) v += dtr[j] * xp[(size_t)j * 768];
    } else if (row < 800){
      v = xproj_w[(size_t)l * 80 * 768 + (size_t)(48 + row - 768) * 768 + k];
    }
    out[idx] = f2bf(v);
  }
}

// ---------------- fused LayerNorm -> xln(f32) + RMSNorm(ln) -> bf16 ----------------
__global__ __launch_bounds__(256) void ln_rms_kernel(const float* __restrict__ in,
                                                     const float* __restrict__ w,
                                                     const float* __restrict__ b,
                                                     const float* __restrict__ rw,
                                                     float* __restrict__ xln,
                                                     u16* __restrict__ outB){
  int row = blockIdx.x;
  const float* x = in + (size_t)row * 768;
  int t = threadIdx.x;
  float v0 = x[t], v1 = x[t + 256], v2 = x[t + 512];
  float s = v0 + v1 + v2;
  float s2 = v0 * v0 + v1 * v1 + v2 * v2;
  #pragma unroll
  for (int off = 1; off < 64; off <<= 1){ s += __shfl_xor(s, off); s2 += __shfl_xor(s2, off); }
  __shared__ float red[8];
  int wid = t >> 6, lane = t & 63;
  if (lane == 0){ red[wid] = s; red[4 + wid] = s2; }
  __syncthreads();
  s = red[0] + red[1] + red[2] + red[3];
  s2 = red[4] + red[5] + red[6] + red[7];
  float mean = s * (1.f / 768.f);
  float var = s2 * (1.f / 768.f) - mean * mean;
  float rstd = rsqrtf(var + 1e-5f);
  float o0 = (v0 - mean) * rstd * w[t] + b[t];
  float o1 = (v1 - mean) * rstd * w[t + 256] + b[t + 256];
  float o2 = (v2 - mean) * rstd * w[t + 512] + b[t + 512];
  xln[(size_t)row * 768 + t]       = o0;
  xln[(size_t)row * 768 + t + 256] = o1;
  xln[(size_t)row * 768 + t + 512] = o2;
  float q = o0 * o0 + o1 * o1 + o2 * o2;
  #pragma unroll
  for (int off = 1; off < 64; off <<= 1){ q += __shfl_xor(q, off); }
  __syncthreads();
  if (lane == 0) red[wid] = q;
  __syncthreads();
  q = red[0] + red[1] + red[2] + red[3];
  float rs = rsqrtf(q * (1.f / 768.f) + 1e-5f);
  outB[(size_t)row * 768 + t]       = f2bf(o0 * rs * rw[t]);
  outB[(size_t)row * 768 + t + 256] = f2bf(o1 * rs * rw[t + 256]);
  outB[(size_t)row * 768 + t + 512] = f2bf(o2 * rs * rw[t + 512]);
}

// ---------------- LayerNorm (row=768) -> bf16 only ----------------
__global__ __launch_bounds__(256) void ln_kernel(const float* __restrict__ in,
                                                 const float* __restrict__ w,
                                                 const float* __restrict__ b,
                                                 u16* __restrict__ outB){
  int row = blockIdx.x;
  const float* x = in + (size_t)row * 768;
  int t = threadIdx.x;
  float v0 = x[t], v1 = x[t + 256], v2 = x[t + 512];
  float s = v0 + v1 + v2;
  float s2 = v0 * v0 + v1 * v1 + v2 * v2;
  #pragma unroll
  for (int off = 1; off < 64; off <<= 1){ s += __shfl_xor(s, off); s2 += __shfl_xor(s2, off); }
  __shared__ float red[8];
  int wid = t >> 6, lane = t & 63;
  if (lane == 0){ red[wid] = s; red[4 + wid] = s2; }
  __syncthreads();
  s = red[0] + red[1] + red[2] + red[3];
  s2 = red[4] + red[5] + red[6] + red[7];
  float mean = s * (1.f / 768.f);
  float var = s2 * (1.f / 768.f) - mean * mean;
  float rstd = rsqrtf(var + 1e-5f);
  #pragma unroll
  for (int j = 0; j < 3; j++){
    int e = t + j * 256;
    float v = (j == 0) ? v0 : (j == 1) ? v1 : v2;
    outB[(size_t)row * 768 + e] = f2bf((v - mean) * rstd * w[e] + b[e]);
  }
}

// ---------------- depthwise causal conv K=4 + bias + SiLU -> bf16 ----------------
__global__ __launch_bounds__(256) void conv_silu(const float* __restrict__ xz,
                                                 const float* __restrict__ cw,
                                                 const float* __restrict__ cb,
                                                 u16* __restrict__ xi){
  int row = blockIdx.x;            // 0..2047
  int b = row >> 10, l = row & 1023;
  for (int e = threadIdx.x; e < 768; e += 256){
    const float* w = cw + (size_t)e * 4;
    float acc = cb[e];
    #pragma unroll
    for (int k = 0; k < 4; k++){
      int ls = l - 3 + k;
      if (ls >= 0) acc += w[k] * xz[((size_t)((b << 10) + ls)) * 1536 + e];
    }
    float sv = acc / (1.f + __expf(-acc));
    xi[(size_t)row * 768 + e] = f2bf(sv);
  }
}

// ---------------- selective scan: pass 1 (chunk summaries) ----------------
__global__ __launch_bounds__(256) void scan_pass1(const float* __restrict__ delta,
                                                  const u16* __restrict__ xi,
                                                  const float* __restrict__ bc,
                                                  const float* __restrict__ A_log,
                                                  float* __restrict__ asum,
                                                  float* __restrict__ bsum){
  int bid = blockIdx.x;
  int eg = bid % 3; int c = (bid / 3) & 63; int b = bid / 192;
  int e = eg * 256 + threadIdx.x;
  float A[16], a[16], s[16];
  const float* al = A_log + (size_t)e * 16;
  #pragma unroll
  for (int n = 0; n < 16; n++){ A[n] = -__expf(al[n]); a[n] = 1.f; s[n] = 0.f; }
  for (int ll = 0; ll < 16; ll++){
    int row = b * 1024 + c * 16 + ll;
    float dlt = delta[(size_t)row * 768 + e];
    float xiv = bf2f(xi[(size_t)row * 768 + e]);
    float du = dlt * xiv;
    const float* bm = bc + (size_t)row * 32;
    #pragma unroll
    for (int n = 0; n < 16; n++){
      float dA = __expf(dlt * A[n]);
      s[n] = dA * s[n] + du * bm[n];
      a[n] *= dA;
    }
  }
  size_t base = (((size_t)(b * 64 + c) * 768) + e) * 16;
  #pragma unroll
  for (int n = 0; n < 16; n++){ asum[base + n] = a[n]; bsum[base + n] = s[n]; }
}

// ---------------- scan pass 2: combine 64 chunk summaries ----------------
__global__ __launch_bounds__(256) void scan_pass2(const float* __restrict__ asum,
                                                  const float* __restrict__ bsum,
                                                  float* __restrict__ h0){
  int idx = blockIdx.x * 256 + threadIdx.x;  // b*12288 + e*16 + n
  int b = idx / 12288;
  int en = idx - b * 12288;
  float h = 0.f;
  for (int c = 0; c < 64; c++){
    size_t i = ((size_t)(b * 64 + c) * 12288) + en;
    h0[i] = h;
    h = asum[i] * h + bsum[i];
  }
}

// ---------------- scan pass 3: rescan with init state + y epilogue ----------------
__global__ __launch_bounds__(256) void scan_pass3(const float* __restrict__ delta,
                                                  const u16* __restrict__ xi,
                                                  const float* __restrict__ bc,
                                                  const float* __restrict__ A_log,
                                                  const float* __restrict__ h0,
                                                  const float* __restrict__ Dp,
                                                  const float* __restrict__ xz,
                                                  u16* __restrict__ y){
  int bid = blockIdx.x;
  int eg = bid % 3; int c = (bid / 3) & 63; int b = bid / 192;
  int e = eg * 256 + threadIdx.x;
  float A[16], s[16];
  const float* al = A_log + (size_t)e * 16;
  #pragma unroll
  for (int n = 0; n < 16; n++) A[n] = -__expf(al[n]);
  size_t base = (((size_t)(b * 64 + c) * 768) + e) * 16;
  #pragma unroll
  for (int n = 0; n < 16; n++) s[n] = h0[base + n];
  float dp = Dp[e];
  for (int ll = 0; ll < 16; ll++){
    int row = b * 1024 + c * 16 + ll;
    float dlt = delta[(size_t)row * 768 + e];
    float xiv = bf2f(xi[(size_t)row * 768 + e]);
    float du = dlt * xiv;
    const float* bm = bc + (size_t)row * 32;
    const float* cm = bm + 16;
    float acc = 0.f;
    #pragma unroll
    for (int n = 0; n < 16; n++){
      float dA = __expf(dlt * A[n]);
      s[n] = dA * s[n] + du * bm[n];
      acc += s[n] * cm[n];
    }
    float yv = acc + dp * xiv;
    float z = xz[(size_t)row * 1536 + 768 + e];
    yv *= z / (1.f + __expf(-z));
    y[(size_t)row * 768 + e] = f2bf(yv);
  }
}

// ---------------- bf16 MFMA GEMM, 64x64 tile, BK=64, depth-2 pipeline, 4 LDS bufs ----
// MODE 0: outF = v + bias? + r1? + r2?  (+ optional outB = bf16(result))
// MODE 1: outB = bf16(relu(v + bias))
// MODE 2: col<768 -> dl = softplus(v+dtb); col<800 -> bco = v; else drop
template<int MODE>
__global__ __launch_bounds__(256) void gemm64(
    const u16* __restrict__ A, const u16* __restrict__ Bw, int N, int Kd,
    float* __restrict__ outF, u16* __restrict__ outB,
    const float* __restrict__ bias, const float* __restrict__ r1,
    const float* __restrict__ r2,
    float* __restrict__ dl, float* __restrict__ bco, const float* __restrict__ dtb){
  __shared__ u16 sm[4][2][64 * 64];   // 64 KB: 4 buffers x {A,B} x 8KB
  const int tid = threadIdx.x;
  const int wid = tid >> 6, lane = tid & 63;
  const int lhi = lane >> 4, llo = lane & 15;
  // XCD-aware bijective swizzle (all grids here have nwg % 8 == 0, gridDim.x == 32)
  int nwg = (int)(gridDim.x * gridDim.y);
  int orig = (int)(blockIdx.y * gridDim.x + blockIdx.x);
  int wg = (orig & 7) * (nwg >> 3) + (orig >> 3);
  int bx = wg & 31;
  int by = wg >> 5;
  const int m0 = bx * 64, n0 = by * 64;
  const int wm = (wid >> 1) * 32, wn = (wid & 1) * 32;
  const int nk = Kd >> 6;
  f32x4 acc[2][2] = {};

  auto stage = [&](int buf, int kt){
    const u16* Ab = A + (size_t)m0 * Kd + kt * 64;
    const u16* Bb = Bw + (size_t)n0 * Kd + kt * 64;
    #pragma unroll
    for (int j = 0; j < 2; j++){
      int sl = j * 256 + tid;
      int row = sl >> 3;
      int ch = (sl & 7) ^ (row & 7);
      __builtin_amdgcn_global_load_lds(
          (const __attribute__((address_space(1))) void*)(Ab + (size_t)row * Kd + ch * 8),
          (__attribute__((address_space(3))) void*)(&sm[buf][0][sl * 8]), 16, 0, 0);
    }
    #pragma unroll
    for (int j = 0; j < 2; j++){
      int sl = j * 256 + tid;
      int row = sl >> 3;
      int ch = (sl & 7) ^ (row & 7);
      __builtin_amdgcn_global_load_lds(
          (const __attribute__((address_space(1))) void*)(Bb + (size_t)row * Kd + ch * 8),
          (__attribute__((address_space(3))) void*)(&sm[buf][1][sl * 8]), 16, 0, 0);
    }
  };

  stage(0, 0);
  stage(1, 1);
  for (int kt = 0; kt < nk; ++kt){
    if (kt + 2 < nk){
      stage((kt + 2) & 3, kt + 2);
      asm volatile("s_waitcnt vmcnt(8)" ::: "memory");   // tile kt landed; kt+1,kt+2 in flight
    } else if (kt + 1 < nk){
      asm volatile("s_waitcnt vmcnt(4)" ::: "memory");   // tile kt landed; kt+1 in flight
    } else {
      asm volatile("s_waitcnt vmcnt(0)" ::: "memory");
    }
    __syncthreads();   // single barrier: read-validity of tile kt + write-safety of kt+2
    const u16* Asb = &sm[kt & 3][0][0];
    const u16* Bsb = &sm[kt & 3][1][0];
    short8 af[2][2], bfr[2][2];
    #pragma unroll
    for (int mi = 0; mi < 2; mi++){
      int row = wm + mi * 16 + llo;
      const u16* rp = Asb + row * 64;
      #pragma unroll
      for (int s2 = 0; s2 < 2; s2++){
        int ch = (s2 * 4 + lhi) ^ (row & 7);
        af[mi][s2] = *(const short8*)(rp + ch * 8);
      }
    }
    #pragma unroll
    for (int ni = 0; ni < 2; ni++){
      int row = wn + ni * 16 + llo;
      const u16* rp = Bsb + row * 64;
      #pragma unroll
      for (int s2 = 0; s2 < 2; s2++){
        int ch = (s2 * 4 + lhi) ^ (row & 7);
        bfr[ni][s2] = *(const short8*)(rp + ch * 8);
      }
    }
    #pragma unroll
    for (int s2 = 0; s2 < 2; s2++)
      #pragma unroll
      for (int mi = 0; mi < 2; mi++)
        #pragma unroll
        for (int ni = 0; ni < 2; ni++)
          acc[mi][ni] = __builtin_amdgcn_mfma_f32_16x16x32_bf16(
              af[mi][s2], bfr[ni][s2], acc[mi][ni], 0, 0, 0);
  }
  // epilogue
  #pragma unroll
  for (int mi = 0; mi < 2; mi++){
    #pragma unroll
    for (int ni = 0; ni < 2; ni++){
      int r0 = m0 + wm + mi * 16 + lhi * 4;
      int c = n0 + wn + ni * 16 + llo;
      #pragma unroll
      for (int r = 0; r < 4; r++){
        int rr = r0 + r;
        float v = acc[mi][ni][r];
        if (MODE == 0){
          size_t idx = (size_t)rr * N + c;
          if (bias) v += bias[c];
          if (r1) v += r1[idx];
          if (r2) v += r2[idx];
          outF[idx] = v;
          if (outB) outB[idx] = f2bf(v);
        } else if (MODE == 1){
          size_t idx = (size_t)rr * N + c;
          v += bias[c];
          outB[idx] = f2bf(v > 0.f ? v : 0.f);
        } else {
          if (c < 768){
            float tv = v + dtb[c];
            dl[(size_t)rr * 768 + c] = (tv > 20.f) ? tv : log1pf(__expf(tv));
          } else if (c < 800){
            bco[(size_t)rr * 32 + (c - 768)] = v;
          }
        }
      }
    }
  }
}

// ------------------------------------------------------------------
extern "C" void kernel_launch(void* const* d_in, const int* in_sizes, int n_in,
                              void* d_out, int out_size, void* d_ws, size_t ws_size,
                              hipStream_t stream){
  (void)in_sizes; (void)n_in; (void)out_size; (void)ws_size;
  const float* x_f       = (const float*)d_in[0];
  const float* in_proj_w = (const float*)d_in[1];
  const float* in_proj_b = (const float*)d_in[2];
  const float* out_proj_w= (const float*)d_in[3];
  const float* out_proj_b= (const float*)d_in[4];
  const float* ln1_w     = (const float*)d_in[5];
  const float* ln1_b     = (const float*)d_in[6];
  const float* ln2_w     = (const float*)d_in[7];
  const float* ln2_b     = (const float*)d_in[8];
  const float* ffn_w1    = (const float*)d_in[9];
  const float* ffn_b1    = (const float*)d_in[10];
  const float* ffn_w2    = (const float*)d_in[11];
  const float* ffn_b2    = (const float*)d_in[12];
  const float* rms_w     = (const float*)d_in[13];
  const float* m_in_w    = (const float*)d_in[14];
  const float* conv_w    = (const float*)d_in[15];
  const float* conv_b    = (const float*)d_in[16];
  const float* xproj_w   = (const float*)d_in[17];
  const float* dt_w      = (const float*)d_in[18];
  const float* dt_b      = (const float*)d_in[19];
  const float* A_log     = (const float*)d_in[20];
  const float* Dp        = (const float*)d_in[21];
  const float* m_out_w   = (const float*)d_in[22];

  char* ws = (char*)d_ws;
  size_t off = 0;
  auto alloc = [&](size_t bytes) -> char* {
    char* p = ws + off;
    off += (bytes + 255) & ~(size_t)255;
    return p;
  };
  u16* wb_inp  = (u16*)alloc((size_t)768 * 512 * 2);
  u16* wb_outp = (u16*)alloc((size_t)512 * 768 * 2);
  u16* wb_min  = (u16*)alloc((size_t)4 * 1536 * 768 * 2);
  u16* wb_mout = (u16*)alloc((size_t)4 * 768 * 768 * 2);
  u16* wb_f1   = (u16*)alloc((size_t)4 * 3072 * 768 * 2);
  u16* wb_f2   = (u16*)alloc((size_t)4 * 768 * 3072 * 2);
  u16* wb_dbc  = (u16*)alloc((size_t)4 * 896 * 768 * 2);
  u16* xbf     = (u16*)alloc((size_t)2048 * 512 * 2);
  float* hA    = (float*)alloc((size_t)2048 * 768 * 4);
  float* hB    = (float*)alloc((size_t)2048 * 768 * 4);
  float* xln   = (float*)alloc((size_t)2048 * 768 * 4);
  u16* xnbf    = (u16*)alloc((size_t)2048 * 768 * 2);
  float* xz    = (float*)alloc((size_t)2048 * 1536 * 4);
  u16* xibf    = (u16*)alloc((size_t)2048 * 768 * 2);
  float* dltb  = (float*)alloc((size_t)2048 * 768 * 4);
  float* bcb   = (float*)alloc((size_t)2048 * 32 * 4);
  float* asum  = (float*)alloc((size_t)2 * 64 * 768 * 16 * 4);
  float* bsum  = (float*)alloc((size_t)2 * 64 * 768 * 16 * 4);
  float* h0    = (float*)alloc((size_t)2 * 64 * 768 * 16 * 4);
  u16* ybf     = (u16*)alloc((size_t)2048 * 768 * 2);
  u16* tbf     = (u16*)alloc((size_t)2048 * 768 * 2);
  u16* f1bf    = (u16*)alloc((size_t)2048 * 3072 * 2);
  u16* hfbf    = (u16*)alloc((size_t)2048 * 768 * 2);

  auto cvt = [&](const float* in, u16* out, size_t n){
    int blocks = (int)((n / 4 + 255) / 256);
    if (blocks > 2048) blocks = 2048;
    cvt_f32_bf16<<<blocks, 256, 0, stream>>>(in, out, (int)n);
  };
  cvt(x_f, xbf, (size_t)2048 * 512);
  cvt(in_proj_w, wb_inp, (size_t)768 * 512);
  cvt(out_proj_w, wb_outp, (size_t)512 * 768);
  cvt(m_in_w, wb_min, (size_t)4 * 1536 * 768);
  cvt(m_out_w, wb_mout, (size_t)4 * 768 * 768);
  cvt(ffn_w1, wb_f1, (size_t)4 * 3072 * 768);
  cvt(ffn_w2, wb_f2, (size_t)4 * 768 * 3072);
  build_dbc<<<2048, 256, 0, stream>>>(dt_w, xproj_w, wb_dbc);

  auto gemm = [&](int mode, const u16* Ain, const u16* Bww, int N, int K,
                  float* oF, u16* oB, const float* bias, const float* rr1,
                  const float* rr2, float* dl, float* bco, const float* dtb){
    dim3 g(2048 / 64, N / 64), blk(256);
    if (mode == 0)
      gemm64<0><<<g, blk, 0, stream>>>(Ain, Bww, N, K, oF, oB, bias, rr1, rr2, dl, bco, dtb);
    else if (mode == 1)
      gemm64<1><<<g, blk, 0, stream>>>(Ain, Bww, N, K, oF, oB, bias, rr1, rr2, dl, bco, dtb);
    else
      gemm64<2><<<g, blk, 0, stream>>>(Ain, Bww, N, K, oF, oB, bias, rr1, rr2, dl, bco, dtb);
  };

  // h = x @ in_proj_w.T + b
  gemm(0, xbf, wb_inp, 768, 512, hA, nullptr, in_proj_b, nullptr, nullptr,
       nullptr, nullptr, nullptr);

  for (int i = 0; i < 4; i++){
    ln_rms_kernel<<<2048, 256, 0, stream>>>(hA, ln1_w + i * 768, ln1_b + i * 768,
                                            rms_w + i * 768, xln, xnbf);
    gemm(0, xnbf, wb_min + (size_t)i * 1536 * 768, 1536, 768, xz, nullptr,
         nullptr, nullptr, nullptr, nullptr, nullptr, nullptr);
    conv_silu<<<2048, 256, 0, stream>>>(xz, conv_w + (size_t)i * 768 * 4,
                                        conv_b + i * 768, xibf);
    gemm(2, xibf, wb_dbc + (size_t)i * 896 * 768, 896, 768, nullptr, nullptr,
         nullptr, nullptr, nullptr, dltb, bcb, dt_b + i * 768);
    scan_pass1<<<384, 256, 0, stream>>>(dltb, xibf, bcb,
                                        A_log + (size_t)i * 768 * 16, asum, bsum);
    scan_pass2<<<96, 256, 0, stream>>>(asum, bsum, h0);
    scan_pass3<<<384, 256, 0, stream>>>(dltb, xibf, bcb,
                                        A_log + (size_t)i * 768 * 16, h0,
                                        Dp + i * 768, xz, ybf);
    // h_mid = h + ln1(h) + y @ m_out_w.T
    gemm(0, ybf, wb_mout + (size_t)i * 768 * 768, 768, 768, hB, nullptr,
         nullptr, hA, xln, nullptr, nullptr, nullptr);
    ln_kernel<<<2048, 256, 0, stream>>>(hB, ln2_w + i * 768, ln2_b + i * 768, tbf);
    gemm(1, tbf, wb_f1 + (size_t)i * 3072 * 768, 3072, 768, nullptr, f1bf,
         ffn_b1 + i * 3072, nullptr, nullptr, nullptr, nullptr, nullptr);
    // last layer: also emit bf16 of h for out_proj (skips a cvt kernel)
    gemm(0, f1bf, wb_f2 + (size_t)i * 768 * 3072, 768, 3072, hA,
         (i == 3) ? hfbf : nullptr, ffn_b2 + i * 768, hB, nullptr,
         nullptr, nullptr, nullptr);
  }
  gemm(0, hfbf, wb_outp, 512, 768, (float*)d_out, nullptr, out_proj_b,
       nullptr, nullptr, nullptr, nullptr, nullptr);
}

// Round 4
// 684.580 us; speedup vs baseline: 1.1405x; 1.1405x over previous
//
#include <hip/hip_runtime.h>
#include <stdint.h>

typedef unsigned short u16;
typedef __attribute__((ext_vector_type(8))) short short8;
typedef __attribute__((ext_vector_type(4))) float f32x4;

static __device__ __forceinline__ u16 f2bf(float f){
  unsigned int x = __float_as_uint(f);
  unsigned int r = (x + 0x7FFFu + ((x >> 16) & 1u)) >> 16;
  return (u16)r;
}
static __device__ __forceinline__ float bf2f(u16 u){
  return __uint_as_float(((unsigned int)u) << 16);
}

// ---------------- convert f32 -> bf16 (vectorized) ----------------
__global__ __launch_bounds__(256) void cvt_f32_bf16(const float* __restrict__ in,
                                                    u16* __restrict__ out, int n){
  int i = (blockIdx.x * 256 + threadIdx.x) * 4;
  int stride = gridDim.x * 256 * 4;
  for (; i < n; i += stride){
    float4 v = *reinterpret_cast<const float4*>(in + i);
    union { u16 u[4]; unsigned long long ll; } o;
    o.u[0] = f2bf(v.x); o.u[1] = f2bf(v.y); o.u[2] = f2bf(v.z); o.u[3] = f2bf(v.w);
    *reinterpret_cast<unsigned long long*>(out + i) = o.ll;
  }
}

// ---------------- build combined [W_delta ; xproj_BC ; pad] (896 x 768) bf16 per layer ----
__global__ __launch_bounds__(256) void build_dbc(const float* __restrict__ dt_w,
                                                 const float* __restrict__ xproj_w,
                                                 u16* __restrict__ out){
  const int total = 4 * 896 * 768;
  for (int idx = blockIdx.x * 256 + threadIdx.x; idx < total; idx += gridDim.x * 256){
    int l = idx / (896 * 768);
    int rem = idx - l * 896 * 768;
    int row = rem / 768;
    int k = rem - row * 768;
    float v = 0.f;
    if (row < 768){
      const float* dtr = dt_w + ((size_t)l * 768 + row) * 48;
      const float* xp  = xproj_w + (size_t)l * 80 * 768 + k;
      #pragma unroll 8
      for (int j = 0; j < 48; j++) v += dtr[j] * xp[(size_t)j * 768];
    } else if (row < 800){
      v = xproj_w[(size_t)l * 80 * 768 + (size_t)(48 + row - 768) * 768 + k];
    }
    out[idx] = f2bf(v);
  }
}

// ---------------- fused LayerNorm -> xln(f32) + RMSNorm(ln) -> bf16 ----------------
__global__ __launch_bounds__(256) void ln_rms_kernel(const float* __restrict__ in,
                                                     const float* __restrict__ w,
                                                     const float* __restrict__ b,
                                                     const float* __restrict__ rw,
                                                     float* __restrict__ xln,
                                                     u16* __restrict__ outB){
  int row = blockIdx.x;
  const float* x = in + (size_t)row * 768;
  int t = threadIdx.x;
  float v0 = x[t], v1 = x[t + 256], v2 = x[t + 512];
  float s = v0 + v1 + v2;
  float s2 = v0 * v0 + v1 * v1 + v2 * v2;
  #pragma unroll
  for (int off = 1; off < 64; off <<= 1){ s += __shfl_xor(s, off); s2 += __shfl_xor(s2, off); }
  __shared__ float red[8];
  int wid = t >> 6, lane = t & 63;
  if (lane == 0){ red[wid] = s; red[4 + wid] = s2; }
  __syncthreads();
  s = red[0] + red[1] + red[2] + red[3];
  s2 = red[4] + red[5] + red[6] + red[7];
  float mean = s * (1.f / 768.f);
  float var = s2 * (1.f / 768.f) - mean * mean;
  float rstd = rsqrtf(var + 1e-5f);
  float o0 = (v0 - mean) * rstd * w[t] + b[t];
  float o1 = (v1 - mean) * rstd * w[t + 256] + b[t + 256];
  float o2 = (v2 - mean) * rstd * w[t + 512] + b[t + 512];
  xln[(size_t)row * 768 + t]       = o0;
  xln[(size_t)row * 768 + t + 256] = o1;
  xln[(size_t)row * 768 + t + 512] = o2;
  float q = o0 * o0 + o1 * o1 + o2 * o2;
  #pragma unroll
  for (int off = 1; off < 64; off <<= 1){ q += __shfl_xor(q, off); }
  __syncthreads();
  if (lane == 0) red[wid] = q;
  __syncthreads();
  q = red[0] + red[1] + red[2] + red[3];
  float rs = rsqrtf(q * (1.f / 768.f) + 1e-5f);
  outB[(size_t)row * 768 + t]       = f2bf(o0 * rs * rw[t]);
  outB[(size_t)row * 768 + t + 256] = f2bf(o1 * rs * rw[t + 256]);
  outB[(size_t)row * 768 + t + 512] = f2bf(o2 * rs * rw[t + 512]);
}

// ---------------- LayerNorm (row=768) -> bf16 only ----------------
__global__ __launch_bounds__(256) void ln_kernel(const float* __restrict__ in,
                                                 const float* __restrict__ w,
                                                 const float* __restrict__ b,
                                                 u16* __restrict__ outB){
  int row = blockIdx.x;
  const float* x = in + (size_t)row * 768;
  int t = threadIdx.x;
  float v0 = x[t], v1 = x[t + 256], v2 = x[t + 512];
  float s = v0 + v1 + v2;
  float s2 = v0 * v0 + v1 * v1 + v2 * v2;
  #pragma unroll
  for (int off = 1; off < 64; off <<= 1){ s += __shfl_xor(s, off); s2 += __shfl_xor(s2, off); }
  __shared__ float red[8];
  int wid = t >> 6, lane = t & 63;
  if (lane == 0){ red[wid] = s; red[4 + wid] = s2; }
  __syncthreads();
  s = red[0] + red[1] + red[2] + red[3];
  s2 = red[4] + red[5] + red[6] + red[7];
  float mean = s * (1.f / 768.f);
  float var = s2 * (1.f / 768.f) - mean * mean;
  float rstd = rsqrtf(var + 1e-5f);
  #pragma unroll
  for (int j = 0; j < 3; j++){
    int e = t + j * 256;
    float v = (j == 0) ? v0 : (j == 1) ? v1 : v2;
    outB[(size_t)row * 768 + e] = f2bf((v - mean) * rstd * w[e] + b[e]);
  }
}

// ---------------- depthwise causal conv K=4 + bias + SiLU -> bf16 ----------------
__global__ __launch_bounds__(256) void conv_silu(const float* __restrict__ xz,
                                                 const float* __restrict__ cw,
                                                 const float* __restrict__ cb,
                                                 u16* __restrict__ xi){
  int row = blockIdx.x;            // 0..2047
  int b = row >> 10, l = row & 1023;
  for (int e = threadIdx.x; e < 768; e += 256){
    const float* w = cw + (size_t)e * 4;
    float acc = cb[e];
    #pragma unroll
    for (int k = 0; k < 4; k++){
      int ls = l - 3 + k;
      if (ls >= 0) acc += w[k] * xz[((size_t)((b << 10) + ls)) * 1536 + e];
    }
    float sv = acc / (1.f + __expf(-acc));
    xi[(size_t)row * 768 + e] = f2bf(sv);
  }
}

// ---------------- selective scan: pass 1 (chunk summaries) ----------------
__global__ __launch_bounds__(256) void scan_pass1(const float* __restrict__ delta,
                                                  const u16* __restrict__ xi,
                                                  const float* __restrict__ bc,
                                                  const float* __restrict__ A_log,
                                                  float* __restrict__ asum,
                                                  float* __restrict__ bsum){
  int bid = blockIdx.x;
  int eg = bid % 3; int c = (bid / 3) & 63; int b = bid / 192;
  int e = eg * 256 + threadIdx.x;
  float A[16], a[16], s[16];
  const float* al = A_log + (size_t)e * 16;
  #pragma unroll
  for (int n = 0; n < 16; n++){ A[n] = -__expf(al[n]); a[n] = 1.f; s[n] = 0.f; }
  for (int ll = 0; ll < 16; ll++){
    int row = b * 1024 + c * 16 + ll;
    float dlt = delta[(size_t)row * 768 + e];
    float xiv = bf2f(xi[(size_t)row * 768 + e]);
    float du = dlt * xiv;
    const float* bm = bc + (size_t)row * 32;
    #pragma unroll
    for (int n = 0; n < 16; n++){
      float dA = __expf(dlt * A[n]);
      s[n] = dA * s[n] + du * bm[n];
      a[n] *= dA;
    }
  }
  size_t base = (((size_t)(b * 64 + c) * 768) + e) * 16;
  #pragma unroll
  for (int n = 0; n < 16; n++){ asum[base + n] = a[n]; bsum[base + n] = s[n]; }
}

// ---------------- scan pass 2: combine 64 chunk summaries ----------------
__global__ __launch_bounds__(256) void scan_pass2(const float* __restrict__ asum,
                                                  const float* __restrict__ bsum,
                                                  float* __restrict__ h0){
  int idx = blockIdx.x * 256 + threadIdx.x;  // b*12288 + e*16 + n
  int b = idx / 12288;
  int en = idx - b * 12288;
  float h = 0.f;
  for (int c = 0; c < 64; c++){
    size_t i = ((size_t)(b * 64 + c) * 12288) + en;
    h0[i] = h;
    h = asum[i] * h + bsum[i];
  }
}

// ---------------- scan pass 3: rescan with init state + y epilogue ----------------
__global__ __launch_bounds__(256) void scan_pass3(const float* __restrict__ delta,
                                                  const u16* __restrict__ xi,
                                                  const float* __restrict__ bc,
                                                  const float* __restrict__ A_log,
                                                  const float* __restrict__ h0,
                                                  const float* __restrict__ Dp,
                                                  const float* __restrict__ xz,
                                                  u16* __restrict__ y){
  int bid = blockIdx.x;
  int eg = bid % 3; int c = (bid / 3) & 63; int b = bid / 192;
  int e = eg * 256 + threadIdx.x;
  float A[16], s[16];
  const float* al = A_log + (size_t)e * 16;
  #pragma unroll
  for (int n = 0; n < 16; n++) A[n] = -__expf(al[n]);
  size_t base = (((size_t)(b * 64 + c) * 768) + e) * 16;
  #pragma unroll
  for (int n = 0; n < 16; n++) s[n] = h0[base + n];
  float dp = Dp[e];
  for (int ll = 0; ll < 16; ll++){
    int row = b * 1024 + c * 16 + ll;
    float dlt = delta[(size_t)row * 768 + e];
    float xiv = bf2f(xi[(size_t)row * 768 + e]);
    float du = dlt * xiv;
    const float* bm = bc + (size_t)row * 32;
    const float* cm = bm + 16;
    float acc = 0.f;
    #pragma unroll
    for (int n = 0; n < 16; n++){
      float dA = __expf(dlt * A[n]);
      s[n] = dA * s[n] + du * bm[n];
      acc += s[n] * cm[n];
    }
    float yv = acc + dp * xiv;
    float z = xz[(size_t)row * 1536 + 768 + e];
    yv *= z / (1.f + __expf(-z));
    y[(size_t)row * 768 + e] = f2bf(yv);
  }
}

// ---------------- bf16 MFMA GEMM, 64x64 tile, BK=64, depth-2, RAW barriers ----------
// Counted vmcnt BEFORE a raw s_barrier keeps prefetch loads in flight across the
// barrier (__syncthreads would drain vmcnt to 0 -> kills the pipeline; m97/m201).
// MODE 0: outF = v + bias? + r1? + r2?  (+ optional outB = bf16(result))
// MODE 1: outB = bf16(relu(v + bias))
// MODE 2: col<768 -> dl = softplus(v+dtb); col<800 -> bco = v; else drop
template<int MODE>
__global__ __launch_bounds__(256) void gemm64(
    const u16* __restrict__ A, const u16* __restrict__ Bw, int N, int Kd,
    float* __restrict__ outF, u16* __restrict__ outB,
    const float* __restrict__ bias, const float* __restrict__ r1,
    const float* __restrict__ r2,
    float* __restrict__ dl, float* __restrict__ bco, const float* __restrict__ dtb){
  __shared__ u16 sm[4][2][64 * 64];   // 64 KB: 4 buffers x {A,B} x 8KB
  const int tid = threadIdx.x;
  const int wid = tid >> 6, lane = tid & 63;
  const int lhi = lane >> 4, llo = lane & 15;
  // XCD-aware bijective swizzle (all grids here have nwg % 8 == 0, gridDim.x == 32)
  int nwg = (int)(gridDim.x * gridDim.y);
  int orig = (int)(blockIdx.y * gridDim.x + blockIdx.x);
  int wg = (orig & 7) * (nwg >> 3) + (orig >> 3);
  int bx = wg & 31;
  int by = wg >> 5;
  const int m0 = bx * 64, n0 = by * 64;
  const int wm = (wid >> 1) * 32, wn = (wid & 1) * 32;
  const int nk = Kd >> 6;
  f32x4 acc[2][2] = {};

  auto stage = [&](int buf, int kt){
    const u16* Ab = A + (size_t)m0 * Kd + kt * 64;
    const u16* Bb = Bw + (size_t)n0 * Kd + kt * 64;
    #pragma unroll
    for (int j = 0; j < 2; j++){
      int sl = j * 256 + tid;
      int row = sl >> 3;
      int ch = (sl & 7) ^ (row & 7);
      __builtin_amdgcn_global_load_lds(
          (const __attribute__((address_space(1))) void*)(Ab + (size_t)row * Kd + ch * 8),
          (__attribute__((address_space(3))) void*)(&sm[buf][0][sl * 8]), 16, 0, 0);
    }
    #pragma unroll
    for (int j = 0; j < 2; j++){
      int sl = j * 256 + tid;
      int row = sl >> 3;
      int ch = (sl & 7) ^ (row & 7);
      __builtin_amdgcn_global_load_lds(
          (const __attribute__((address_space(1))) void*)(Bb + (size_t)row * Kd + ch * 8),
          (__attribute__((address_space(3))) void*)(&sm[buf][1][sl * 8]), 16, 0, 0);
    }
  };

  stage(0, 0);
  stage(1, 1);
  for (int kt = 0; kt < nk; ++kt){
    if (kt + 2 < nk){
      stage((kt + 2) & 3, kt + 2);
      asm volatile("s_waitcnt vmcnt(8)" ::: "memory");   // tile kt landed; kt+1,kt+2 in flight
    } else if (kt + 1 < nk){
      asm volatile("s_waitcnt vmcnt(4)" ::: "memory");   // tile kt landed; kt+1 in flight
    } else {
      asm volatile("s_waitcnt vmcnt(0)" ::: "memory");
    }
    __builtin_amdgcn_s_barrier();          // RAW barrier: no implicit vmcnt(0) drain
    __builtin_amdgcn_sched_barrier(0);     // fence: nothing hoisted above the barrier
    const u16* Asb = &sm[kt & 3][0][0];
    const u16* Bsb = &sm[kt & 3][1][0];
    short8 af[2][2], bfr[2][2];
    #pragma unroll
    for (int mi = 0; mi < 2; mi++){
      int row = wm + mi * 16 + llo;
      const u16* rp = Asb + row * 64;
      #pragma unroll
      for (int s2 = 0; s2 < 2; s2++){
        int ch = (s2 * 4 + lhi) ^ (row & 7);
        af[mi][s2] = *(const short8*)(rp + ch * 8);
      }
    }
    #pragma unroll
    for (int ni = 0; ni < 2; ni++){
      int row = wn + ni * 16 + llo;
      const u16* rp = Bsb + row * 64;
      #pragma unroll
      for (int s2 = 0; s2 < 2; s2++){
        int ch = (s2 * 4 + lhi) ^ (row & 7);
        bfr[ni][s2] = *(const short8*)(rp + ch * 8);
      }
    }
    #pragma unroll
    for (int s2 = 0; s2 < 2; s2++)
      #pragma unroll
      for (int mi = 0; mi < 2; mi++)
        #pragma unroll
        for (int ni = 0; ni < 2; ni++)
          acc[mi][ni] = __builtin_amdgcn_mfma_f32_16x16x32_bf16(
              af[mi][s2], bfr[ni][s2], acc[mi][ni], 0, 0, 0);
  }
  // epilogue
  #pragma unroll
  for (int mi = 0; mi < 2; mi++){
    #pragma unroll
    for (int ni = 0; ni < 2; ni++){
      int r0 = m0 + wm + mi * 16 + lhi * 4;
      int c = n0 + wn + ni * 16 + llo;
      #pragma unroll
      for (int r = 0; r < 4; r++){
        int rr = r0 + r;
        float v = acc[mi][ni][r];
        if (MODE == 0){
          size_t idx = (size_t)rr * N + c;
          if (bias) v += bias[c];
          if (r1) v += r1[idx];
          if (r2) v += r2[idx];
          outF[idx] = v;
          if (outB) outB[idx] = f2bf(v);
        } else if (MODE == 1){
          size_t idx = (size_t)rr * N + c;
          v += bias[c];
          outB[idx] = f2bf(v > 0.f ? v : 0.f);
        } else {
          if (c < 768){
            float tv = v + dtb[c];
            dl[(size_t)rr * 768 + c] = (tv > 20.f) ? tv : log1pf(__expf(tv));
          } else if (c < 800){
            bco[(size_t)rr * 32 + (c - 768)] = v;
          }
        }
      }
    }
  }
}

// ------------------------------------------------------------------
extern "C" void kernel_launch(void* const* d_in, const int* in_sizes, int n_in,
                              void* d_out, int out_size, void* d_ws, size_t ws_size,
                              hipStream_t stream){
  (void)in_sizes; (void)n_in; (void)out_size; (void)ws_size;
  const float* x_f       = (const float*)d_in[0];
  const float* in_proj_w = (const float*)d_in[1];
  const float* in_proj_b = (const float*)d_in[2];
  const float* out_proj_w= (const float*)d_in[3];
  const float* out_proj_b= (const float*)d_in[4];
  const float* ln1_w     = (const float*)d_in[5];
  const float* ln1_b     = (const float*)d_in[6];
  const float* ln2_w     = (const float*)d_in[7];
  const float* ln2_b     = (const float*)d_in[8];
  const float* ffn_w1    = (const float*)d_in[9];
  const float* ffn_b1    = (const float*)d_in[10];
  const float* ffn_w2    = (const float*)d_in[11];
  const float* ffn_b2    = (const float*)d_in[12];
  const float* rms_w     = (const float*)d_in[13];
  const float* m_in_w    = (const float*)d_in[14];
  const float* conv_w    = (const float*)d_in[15];
  const float* conv_b    = (const float*)d_in[16];
  const float* xproj_w   = (const float*)d_in[17];
  const float* dt_w      = (const float*)d_in[18];
  const float* dt_b      = (const float*)d_in[19];
  const float* A_log     = (const float*)d_in[20];
  const float* Dp        = (const float*)d_in[21];
  const float* m_out_w   = (const float*)d_in[22];

  char* ws = (char*)d_ws;
  size_t off = 0;
  auto alloc = [&](size_t bytes) -> char* {
    char* p = ws + off;
    off += (bytes + 255) & ~(size_t)255;
    return p;
  };
  u16* wb_inp  = (u16*)alloc((size_t)768 * 512 * 2);
  u16* wb_outp = (u16*)alloc((size_t)512 * 768 * 2);
  u16* wb_min  = (u16*)alloc((size_t)4 * 1536 * 768 * 2);
  u16* wb_mout = (u16*)alloc((size_t)4 * 768 * 768 * 2);
  u16* wb_f1   = (u16*)alloc((size_t)4 * 3072 * 768 * 2);
  u16* wb_f2   = (u16*)alloc((size_t)4 * 768 * 3072 * 2);
  u16* wb_dbc  = (u16*)alloc((size_t)4 * 896 * 768 * 2);
  u16* xbf     = (u16*)alloc((size_t)2048 * 512 * 2);
  float* hA    = (float*)alloc((size_t)2048 * 768 * 4);
  float* hB    = (float*)alloc((size_t)2048 * 768 * 4);
  float* xln   = (float*)alloc((size_t)2048 * 768 * 4);
  u16* xnbf    = (u16*)alloc((size_t)2048 * 768 * 2);
  float* xz    = (float*)alloc((size_t)2048 * 1536 * 4);
  u16* xibf    = (u16*)alloc((size_t)2048 * 768 * 2);
  float* dltb  = (float*)alloc((size_t)2048 * 768 * 4);
  float* bcb   = (float*)alloc((size_t)2048 * 32 * 4);
  float* asum  = (float*)alloc((size_t)2 * 64 * 768 * 16 * 4);
  float* bsum  = (float*)alloc((size_t)2 * 64 * 768 * 16 * 4);
  float* h0    = (float*)alloc((size_t)2 * 64 * 768 * 16 * 4);
  u16* ybf     = (u16*)alloc((size_t)2048 * 768 * 2);
  u16* tbf     = (u16*)alloc((size_t)2048 * 768 * 2);
  u16* f1bf    = (u16*)alloc((size_t)2048 * 3072 * 2);
  u16* hfbf    = (u16*)alloc((size_t)2048 * 768 * 2);

  auto cvt = [&](const float* in, u16* out, size_t n){
    int blocks = (int)((n / 4 + 255) / 256);
    if (blocks > 2048) blocks = 2048;
    cvt_f32_bf16<<<blocks, 256, 0, stream>>>(in, out, (int)n);
  };
  cvt(x_f, xbf, (size_t)2048 * 512);
  cvt(in_proj_w, wb_inp, (size_t)768 * 512);
  cvt(out_proj_w, wb_outp, (size_t)512 * 768);
  cvt(m_in_w, wb_min, (size_t)4 * 1536 * 768);
  cvt(m_out_w, wb_mout, (size_t)4 * 768 * 768);
  cvt(ffn_w1, wb_f1, (size_t)4 * 3072 * 768);
  cvt(ffn_w2, wb_f2, (size_t)4 * 768 * 3072);
  build_dbc<<<2048, 256, 0, stream>>>(dt_w, xproj_w, wb_dbc);

  auto gemm = [&](int mode, const u16* Ain, const u16* Bww, int N, int K,
                  float* oF, u16* oB, const float* bias, const float* rr1,
                  const float* rr2, float* dl, float* bco, const float* dtb){
    dim3 g(2048 / 64, N / 64), blk(256);
    if (mode == 0)
      gemm64<0><<<g, blk, 0, stream>>>(Ain, Bww, N, K, oF, oB, bias, rr1, rr2, dl, bco, dtb);
    else if (mode == 1)
      gemm64<1><<<g, blk, 0, stream>>>(Ain, Bww, N, K, oF, oB, bias, rr1, rr2, dl, bco, dtb);
    else
      gemm64<2><<<g, blk, 0, stream>>>(Ain, Bww, N, K, oF, oB, bias, rr1, rr2, dl, bco, dtb);
  };

  // h = x @ in_proj_w.T + b
  gemm(0, xbf, wb_inp, 768, 512, hA, nullptr, in_proj_b, nullptr, nullptr,
       nullptr, nullptr, nullptr);

  for (int i = 0; i < 4; i++){
    ln_rms_kernel<<<2048, 256, 0, stream>>>(hA, ln1_w + i * 768, ln1_b + i * 768,
                                            rms_w + i * 768, xln, xnbf);
    gemm(0, xnbf, wb_min + (size_t)i * 1536 * 768, 1536, 768, xz, nullptr,
         nullptr, nullptr, nullptr, nullptr, nullptr, nullptr);
    conv_silu<<<2048, 256, 0, stream>>>(xz, conv_w + (size_t)i * 768 * 4,
                                        conv_b + i * 768, xibf);
    gemm(2, xibf, wb_dbc + (size_t)i * 896 * 768, 896, 768, nullptr, nullptr,
         nullptr, nullptr, nullptr, dltb, bcb, dt_b + i * 768);
    scan_pass1<<<384, 256, 0, stream>>>(dltb, xibf, bcb,
                                        A_log + (size_t)i * 768 * 16, asum, bsum);
    scan_pass2<<<96, 256, 0, stream>>>(asum, bsum, h0);
    scan_pass3<<<384, 256, 0, stream>>>(dltb, xibf, bcb,
                                        A_log + (size_t)i * 768 * 16, h0,
                                        Dp + i * 768, xz, ybf);
    // h_mid = h + ln1(h) + y @ m_out_w.T
    gemm(0, ybf, wb_mout + (size_t)i * 768 * 768, 768, 768, hB, nullptr,
         nullptr, hA, xln, nullptr, nullptr, nullptr);
    ln_kernel<<<2048, 256, 0, stream>>>(hB, ln2_w + i * 768, ln2_b + i * 768, tbf);
    gemm(1, tbf, wb_f1 + (size_t)i * 3072 * 768, 3072, 768, nullptr, f1bf,
         ffn_b1 + i * 3072, nullptr, nullptr, nullptr, nullptr, nullptr);
    // last layer: also emit bf16 of h for out_proj (skips a cvt kernel)
    gemm(0, f1bf, wb_f2 + (size_t)i * 768 * 3072, 768, 3072, hA,
         (i == 3) ? hfbf : nullptr, ffn_b2 + i * 768, hB, nullptr,
         nullptr, nullptr, nullptr);
  }
  gemm(0, hfbf, wb_outp, 512, 768, (float*)d_out, nullptr, out_proj_b,
       nullptr, nullptr, nullptr, nullptr, nullptr);
}